// Round 1
// 372.861 us; speedup vs baseline: 1.0388x; 1.0388x over previous
//
#include <hip/hip_runtime.h>

#define N_ 4
#define D_ 16
#define H_ 112
#define W_ 112
#define C_ 64

#define DO_ 2
#define HO_ 2
#define DT_ (D_ / DO_)                     // 8 d-tiles
#define HTILES (H_ / HO_)                  // 56 h-tiles
#define WAVES_PER_BLOCK 4
#define HGROUPS (HTILES / WAVES_PER_BLOCK) // 14
#define WSPLIT 4                           // was 2: 2x the waves -> 28 waves/CU of work
#define WQ (W_ / WSPLIT)                   // 28 output columns per wave
#define NWG (N_ * DT_ * HGROUPS * WSPLIT)  // 1792 blocks
#define CB (C_ * 4)                        // 256 B: one (w) column step per lane-channel

// Zero page for SAME-padding halo rows: .bss device globals are zero-initialized
// at module load and never written -> masked streams read real zeros, no mask mul.
__device__ float zpage[W_ * C_];

// Register sliding-window depthwise 3D conv, latency-optimized:
//  - lane = channel (C=64 == wave width): every access 256B coalesced
//  - stream bases are wave-uniform SGPR pairs (readfirstlane'd wid), one shared
//    per-lane 32-bit byte offset vb -> saddr-form loads, 1 VALU add/step
//  - explicit nxt[] prefetch at top of step: load col w+2, compute cols w-1..w+1,
//    rotate at bottom -> one full step of cover for the 16 in-flight loads
__global__ __launch_bounds__(256, 4)
void dwconv3d_kernel(const float* __restrict__ x,
                     const float* __restrict__ wgt,
                     float* __restrict__ out) {
    // bijective XCD-aware swizzle (NWG % 8 == 0): each XCD gets a contiguous
    // 224-block chunk -> halo-sharing (wh,hg,dt) neighbors hit the same L2
    int b = blockIdx.x;
    b = (b & 7) * (NWG / 8) + (b >> 3);
    const int wh = b % WSPLIT; b /= WSPLIT;
    const int hg = b % HGROUPS; b /= HGROUPS;
    const int dt = b % DT_;     b /= DT_;
    const int n  = b;

    const int c   = threadIdx.x & 63;
    const int wid = __builtin_amdgcn_readfirstlane(threadIdx.x >> 6); // force SGPR

    const int d0 = dt * DO_;
    const int h0 = (hg * WAVES_PER_BLOCK + wid) * HO_;
    const int w0 = wh * WQ;

    // per-lane weights wt[kd][kh][kw] (27 VGPRs), coalesced 256B loads
    float wt[3][3][3];
#pragma unroll
    for (int kd = 0; kd < 3; ++kd)
#pragma unroll
      for (int kh = 0; kh < 3; ++kh)
#pragma unroll
        for (int kw = 0; kw < 3; ++kw)
          wt[kd][kh][kw] = wgt[((kd * 3 + kh) * 3 + kw) * C_ + c];

    // 16 wave-uniform stream bases: row (d,h) start of x, or the zero page
    const char* bx[4][4];
#pragma unroll
    for (int dr = 0; dr < 4; ++dr) {
      const int d = d0 - 1 + dr;
#pragma unroll
      for (int hr = 0; hr < 4; ++hr) {
        const int h = h0 - 1 + hr;
        if (d >= 0 && d < D_ && h >= 0 && h < H_)
          bx[dr][hr] = (const char*)(x + (size_t)((n * D_ + d) * H_ + h) * W_ * C_);
        else
          bx[dr][hr] = (const char*)zpage;
      }
    }

    // 4 wave-uniform output row bases (all outputs always in-range)
    char* ox[2][2];
#pragma unroll
    for (int od = 0; od < 2; ++od)
#pragma unroll
      for (int oh = 0; oh < 2; ++oh)
        ox[od][oh] = (char*)(out +
            (size_t)((n * D_ + d0 + od) * H_ + (h0 + oh)) * W_ * C_);

    // shared per-lane byte offset; during step w it equals (w+2)*CB + c*4
    unsigned vb = (unsigned)((w0 + 2) * CB) + (unsigned)(c * 4);

    // window win[wslot][dr][hr]: wslot 0/1/2 = cols w-1, w, w+1
    float win[3][4][4];
#pragma unroll
    for (int dr = 0; dr < 4; ++dr)
#pragma unroll
      for (int hr = 0; hr < 4; ++hr) {
        win[1][dr][hr] = *(const float*)(bx[dr][hr] + (vb - 2 * CB));
        win[2][dr][hr] = *(const float*)(bx[dr][hr] + (vb - 1 * CB));
        win[0][dr][hr] = 0.0f;
      }
    if (w0 != 0) {
#pragma unroll
      for (int dr = 0; dr < 4; ++dr)
#pragma unroll
        for (int hr = 0; hr < 4; ++hr)
          win[0][dr][hr] = *(const float*)(bx[dr][hr] + (vb - 3 * CB));
    }

#pragma unroll 4
    for (int w = w0; w < w0 + WQ; ++w) {
      // ---- prefetch col w+2 (issued before FMAs -> a full step of latency cover)
      float nxt[4][4];
      if (w + 2 < W_) {  // wave-uniform
#pragma unroll
        for (int dr = 0; dr < 4; ++dr)
#pragma unroll
          for (int hr = 0; hr < 4; ++hr)
            nxt[dr][hr] = *(const float*)(bx[dr][hr] + vb);
      } else {
#pragma unroll
        for (int dr = 0; dr < 4; ++dr)
#pragma unroll
          for (int hr = 0; hr < 4; ++hr)
            nxt[dr][hr] = 0.0f;
      }

      // ---- 108 FMAs on cols w-1..w+1 (kw outermost: newest col consumed last)
      float acc[2][2] = {{0.0f, 0.0f}, {0.0f, 0.0f}};
#pragma unroll
      for (int kw = 0; kw < 3; ++kw)
#pragma unroll
        for (int kd = 0; kd < 3; ++kd)
#pragma unroll
          for (int kh = 0; kh < 3; ++kh)
#pragma unroll
            for (int od = 0; od < 2; ++od)
#pragma unroll
              for (int oh = 0; oh < 2; ++oh)
                acc[od][oh] += win[kw][od + kd][oh + kh] * wt[kd][kh][kw];

      // ---- store col w (offset = vb - 2*CB, folds into the 13-bit signed imm)
#pragma unroll
      for (int od = 0; od < 2; ++od)
#pragma unroll
        for (int oh = 0; oh < 2; ++oh)
          *(float*)(ox[od][oh] + (vb - 2 * CB)) = acc[od][oh];

      // ---- rotate window (renamed away under unroll)
#pragma unroll
      for (int dr = 0; dr < 4; ++dr)
#pragma unroll
        for (int hr = 0; hr < 4; ++hr) {
          win[0][dr][hr] = win[1][dr][hr];
          win[1][dr][hr] = win[2][dr][hr];
          win[2][dr][hr] = nxt[dr][hr];
        }
      vb += CB;
    }
}

extern "C" void kernel_launch(void* const* d_in, const int* in_sizes, int n_in,
                              void* d_out, int out_size, void* d_ws, size_t ws_size,
                              hipStream_t stream) {
    const float* x   = (const float*)d_in[0];
    const float* wgt = (const float*)d_in[1];
    float* out = (float*)d_out;

    dim3 grid(NWG);   // 4*8*14*4 = 1792 blocks = 7168 waves = 28 waves/CU of work
    dim3 block(256);
    dwconv3d_kernel<<<grid, block, 0, stream>>>(x, wgt, out);
}